// Round 18
// baseline (156.652 us; speedup 1.0000x reference)
//
#include <hip/hip_runtime.h>
#include <hip/hip_bf16.h>

// DynamicFilter fused, R32 = R31 (verified 78.8us) with epilogue image reads
// moved LDS -> global (L1-hot), xs0f deleted.
//
// R31 confirm: 78.8us stable. Budget: LDS pipe ~75% busy (conv2 7.7K +
// gather 5.2K + hs-wr 2.6K + EPILOGUE 1.5K + stage 0.55K = 17.5K of 23.6K
// cyc/CU/iter-set); VMEM/HBM 6.6% idle, VALU 36%. R32 shifts the epilogue's
// 16 image reads/lane to global loads (data is L1/L2-hot from prefetch):
// -1.5K LDS read + -0.55K xs0f-write cyc, LDS 38.4->34.3KB. Cost: ~8 VALU +
// 1 L1 load per value at epilogue tail (no regs carried across conv2; fy/fx
// packed 1 reg). Bounds predicate reproduces zero-pad exactly; f>=9 terms
// exact-zero via acc=b2r=0 (fy/fx computed uniformly, prediate covers OOB).
// Predict: main 78.8 -> 75-77us, VALUBusy ~42%, WRITE exactly 8192KB,
// VGPR 128 no spill. PRE-COMMIT: neutral/regression -> R31 is the floor,
// revert and conclude.
//
// d_ws: w1c bf16 [32ch][64k] @0 (k-perm layout), w2t bf16 [25tap][16f]
// [32chpos] @4096 (f>=9 zero; chpos 2i->ch i, 2i+1->ch 16+i).
// k-perm: k = s*32+kg*8+2*j+ci ; s0: tap=(kg,j); s1,kg0: tap=(4,j);
// s1,kg1: tap=(j,4); s1,kg2,j0: tap=(4,4); else invalid (w1c=0).

typedef __attribute__((ext_vector_type(8))) short bf16x8;
typedef __attribute__((ext_vector_type(4))) float f32x4;

#define HH 512
#define WW 512
#define TILE 16
#define XS_H 24
#define XS_W 24
#define XS_N (XS_H * XS_W)     // 576
#define HS_R 20
#define HS_C 20
#define PXS 40                 // shorts per px in hs (80B stride)

__device__ __forceinline__ unsigned short f2bf(float x) {
    union { float f; unsigned int u; } v; v.f = x;
    unsigned int u = v.u;
    u += 0x7FFFu + ((u >> 16) & 1u);   // round-to-nearest-even
    return (unsigned short)(u >> 16);
}

__device__ __forceinline__ unsigned int pack_bf2(float a, float b) {
    __hip_bfloat162 h2 = __float22bfloat162_rn(make_float2(a, b));
    union { __hip_bfloat162 h; unsigned int u; } cv; cv.h = h2;
    return cv.u;
}

__device__ __forceinline__ bf16x8 dw4_to_frag(unsigned int d0, unsigned int d1,
                                              unsigned int d2, unsigned int d3) {
    union { unsigned int u[4]; bf16x8 f; } cv;
    cv.u[0] = d0; cv.u[1] = d1; cv.u[2] = d2; cv.u[3] = d3;
    return cv.f;
}

__global__ void dynfilt_prep(const float* __restrict__ w1,
                             const float* __restrict__ w2,
                             unsigned short* __restrict__ w1c,
                             unsigned short* __restrict__ w2t)
{
    int gid = blockIdx.x * 256 + threadIdx.x;   // 8192 threads
    // w1c[ch32][k64] with k-perm (see header); invalid slots -> 0
    for (int i = gid; i < 32 * 64; i += 8192) {
        int ch = i >> 6, k = i & 63;
        int s = (k >> 5) & 1, kg = (k >> 3) & 3, j = (k >> 1) & 3, ci = k & 1;
        int tap = 0; bool val = true;
        if (!s)            tap = kg * 5 + j;        // rows 0-3, cols 0-3
        else if (kg == 0)  tap = 20 + j;            // row 4, cols 0-3
        else if (kg == 1)  tap = j * 5 + 4;         // col 4, rows 0-3
        else if (kg == 2) { tap = 24; val = (j == 0); }   // corner (4,4)
        else               val = false;
        w1c[i] = val ? f2bf(w1[(ch * 2 + ci) * 25 + tap]) : (unsigned short)0;
    }
    // w2t[tap25][f16][chpos32]: chpos 2i -> ch i, 2i+1 -> ch 16+i; f>=9 zero
    for (int i = gid; i < 25 * 16 * 32; i += 8192) {
        int p = i & 31;
        int f = (i >> 5) & 15;
        int tap = i >> 9;   // 0..24
        int ch = (p & 1) * 16 + (p >> 1);
        w2t[i] = (f < 9) ? f2bf(w2[(f * 32 + ch) * 25 + tap]) : (unsigned short)0;
    }
}

// conv2 pass over single tap-col TC0: rolling 4-row B-frag buffer.
// B-frag(row = wv*4 + i + tr, col = n + TC0) shared across (i,tr) with equal
// i+tr; rows rotate through R[.&3]. All indices compile-time after unroll.
template<int TC0>
__device__ __forceinline__ void conv2_pass(const unsigned short* hsp,
                                           const unsigned short* __restrict__ w2t,
                                           int wv, int n, int kg, f32x4* acc) {
    bf16x8 R[4];
    #pragma unroll
    for (int q = 0; q < 4; ++q)
        R[q] = *(const bf16x8*)(hsp + ((wv * 4 + q) * HS_C + n + TC0) * PXS + kg * 8);
    #pragma unroll
    for (int tr = 0; tr < 5; ++tr) {
        bf16x8 afr = *(const bf16x8*)(w2t + ((tr * 5 + TC0) * 16 + n) * 32 + kg * 8);
        #pragma unroll
        for (int i = 0; i < 4; ++i)
            acc[i] = __builtin_amdgcn_mfma_f32_16x16x32_bf16(afr, R[(tr + i) & 3], acc[i], 0, 0, 0);
        if (tr < 4)
            R[tr & 3] = *(const bf16x8*)(hsp + ((wv * 4 + tr + 4) * HS_C + n + TC0) * PXS + kg * 8);
    }
}

__global__
__attribute__((amdgpu_flat_work_group_size(256, 256), amdgpu_waves_per_eu(2)))
void dynfilt_main(const float* __restrict__ image,
                  const float* __restrict__ refer,
                  const float* __restrict__ b1,
                  const float* __restrict__ b2,
                  const unsigned short* __restrict__ w1c,
                  const unsigned short* __restrict__ w2t,
                  float* __restrict__ out)
{
    __shared__ unsigned int pxc[XS_N];          // packed (bf16 img | bf16 ref)
    __shared__ __align__(16) unsigned short hs[HS_R * HS_C * PXS];

    const int t   = threadIdx.x;
    const int gx0 = blockIdx.x * TILE;
    const int gy0 = blockIdx.y * TILE;

    // ---- batch-invariant staging offsets (sentinel -1 = skip) ----
    int soff[3];
    #pragma unroll
    for (int k = 0; k < 3; ++k) {
        int idx = t + k * 256;
        int r = idx / XS_W, c = idx - (idx / XS_W) * XS_W;
        int gy = gy0 - 4 + r, gx = gx0 - 4 + c;
        bool inb = (idx < XS_N) & ((unsigned)gy < HH) & ((unsigned)gx < WW);
        soff[k] = inb ? (gy * WW + gx) : -1;
    }

    const int lane = t & 63;
    const int wv   = t >> 6;
    const int n    = lane & 15;
    const int kg   = lane >> 4;

    // ---- conv1 B-frags: loaded ONCE, carried (w1c L1-hot) ----
    bf16x8 bfr[2][2];
    #pragma unroll
    for (int nt = 0; nt < 2; ++nt)
        #pragma unroll
        for (int s = 0; s < 2; ++s)
            bfr[nt][s] = *(const bf16x8*)(w1c + (nt * 16 + n) * 64 + s * 32 + kg * 8);

    // ---- a1 gather offsets (k-perm layout), packed 4x8bit; invalid -> 0
    //      (broadcast read, zero weight in w1c makes the product exact-0) ----
    unsigned int a1opk = 0;
    #pragma unroll
    for (int j = 0; j < 4; ++j) {
        int o = (kg == 0) ? (4 * XS_W + j)                  // row 4, col j
              : (kg == 1) ? (j * XS_W + 4)                  // row j, col 4
              : (kg == 2 && j == 0) ? (4 * XS_W + 4) : 0;   // corner / dummy
        a1opk |= (unsigned)o << (8 * j);
    }

    // ---- batch-invariant conv1 OOB mask: bit (m*4+r) = h px in-bounds ----
    unsigned int obmask = 0;
    #pragma unroll
    for (int m = 0; m < 7; ++m) {
        #pragma unroll
        for (int r = 0; r < 4; ++r) {
            int px = m * 64 + wv * 16 + kg * 4 + r;
            if (px < 400) {
                int prr = px / HS_C, pcc = px - prr * HS_C;
                int gy = gy0 - 2 + prr, gx = gx0 - 2 + pcc;
                if (((unsigned)gy < HH) & ((unsigned)gx < WW))
                    obmask |= 1u << (m * 4 + r);
            }
        }
    }

    // px = mt*16 + n raster start (pr0,pc0) over 20-wide h grid
    int px0 = wv * 16 + n;
    const int pr0 = px0 / 20, pc0 = px0 - (px0 / 20) * 20;

    const float bb0 = b1[n], bb1 = b1[16 + n];

    // ---- conv2 / epilogue constants (once).
    //      b2r zeroed for f>=9 (terms exact-zero: w2t rows f>=9 are 0 so
    //      acc stays b2r). fy/fx for ALL f packed 4x(fy<<4|fx) in one reg;
    //      epilogue bounds predicate handles any OOB incl. f>=9 dummies. ----
    float b2r[4];
    unsigned int fppk = 0;
    #pragma unroll
    for (int r2 = 0; r2 < 4; ++r2) {
        int f = kg * 4 + r2;
        b2r[r2] = (f < 9) ? b2[f] : 0.f;
        int fy = f / 3, fx = f - fy * 3;          // f>=9: fy 3..5 (dummy)
        fppk |= (unsigned)((fy << 4) | fx) << (8 * r2);
    }

    // ---- prefetch batch 0 halo into regs ----
    float pvI[3], pvR[3];
    #pragma unroll
    for (int k = 0; k < 3; ++k) {
        pvI[k] = 0.f; pvR[k] = 0.f;
        if (soff[k] >= 0) {
            pvI[k] = image[soff[k]];
            pvR[k] = refer[soff[k]];
        }
    }

    #pragma unroll 1
    for (int bb = 0; bb < 8; ++bb) {
        // ---- stage write from prefetch regs (pxc only; xs0f deleted) ----
        #pragma unroll
        for (int k = 0; k < 3; ++k) {
            int idx = t + k * 256;
            if (idx < XS_N)
                pxc[idx] = pack_bf2(pvI[k], pvR[k]);
        }
        __syncthreads();   // A: pxc ready

        // ---- issue next batch's prefetch (hides under conv1+conv2) ----
        if (bb < 7) {
            const float* ibn = image + (size_t)(bb + 1) * (HH * WW);
            const float* rbn = refer + (size_t)(bb + 1) * (HH * WW);
            #pragma unroll
            for (int k = 0; k < 3; ++k) {
                pvI[k] = 0.f; pvR[k] = 0.f;
                if (soff[k] >= 0) {
                    pvI[k] = ibn[soff[k]];
                    pvR[k] = rbn[soff[k]];
                }
            }
        }

        // ---- unpack a1 offsets (conv1-local regs) ----
        int a1o[4];
        #pragma unroll
        for (int j = 0; j < 4; ++j)
            a1o[j] = (int)((a1opk >> (8 * j)) & 0xFFu);

        // ---- conv1 GEMM + fused leaky+pack write to hs (UNIFIED path) ----
        int pr = pr0, pc = pc0;
        unsigned short* hp0 = hs + (wv * 16 + kg * 4) * PXS + 2 * n;
        #pragma unroll
        for (int m = 0; m < 7; ++m) {
            int mt = m * 4 + wv;
            if (mt < 25) {   // wave-uniform guard
                const unsigned int* base = pxc + (pr * XS_W + pc);
                const unsigned int* a0p  = base + kg * XS_W;   // row kg
                unsigned int a0d[4], a1d[4];
                #pragma unroll
                for (int j = 0; j < 4; ++j) a0d[j] = a0p[j];
                #pragma unroll
                for (int j = 0; j < 4; ++j) a1d[j] = base[a1o[j]];
                bf16x8 a0 = dw4_to_frag(a0d[0], a0d[1], a0d[2], a0d[3]);
                bf16x8 a1 = dw4_to_frag(a1d[0], a1d[1], a1d[2], a1d[3]);
                f32x4 d0 = (f32x4){bb0, bb0, bb0, bb0};
                f32x4 d1 = (f32x4){bb1, bb1, bb1, bb1};
                d0 = __builtin_amdgcn_mfma_f32_16x16x32_bf16(a0, bfr[0][0], d0, 0, 0, 0);
                d0 = __builtin_amdgcn_mfma_f32_16x16x32_bf16(a1, bfr[0][1], d0, 0, 0, 0);
                d1 = __builtin_amdgcn_mfma_f32_16x16x32_bf16(a0, bfr[1][0], d1, 0, 0, 0);
                d1 = __builtin_amdgcn_mfma_f32_16x16x32_bf16(a1, bfr[1][1], d1, 0, 0, 0);
                #pragma unroll
                for (int r = 0; r < 4; ++r) {
                    float h0 = fmaxf(d0[r], 0.1f * d0[r]);
                    float h1 = fmaxf(d1[r], 0.1f * d1[r]);
                    if (!((obmask >> (m * 4 + r)) & 1u)) { h0 = 0.f; h1 = 0.f; }
                    *(unsigned int*)(hp0 + (m * 64 + r) * PXS) = pack_bf2(h0, h1);
                }
            }
            pc += 4; pr += 3;
            int w = (pc >= 20) ? 1 : 0;
            pc -= 20 * w; pr += w;
        }
        __syncthreads();   // B: hs ready

        // ---- conv2: rolling-row MFMA GEMM (5 single-col passes), b2-init ----
        f32x4 acc[4];
        #pragma unroll
        for (int i = 0; i < 4; ++i)
            acc[i] = (f32x4){b2r[0], b2r[1], b2r[2], b2r[3]};

        conv2_pass<0>(hs, w2t, wv, n, kg, acc);
        conv2_pass<1>(hs, w2t, wv, n, kg, acc);
        conv2_pass<2>(hs, w2t, wv, n, kg, acc);
        conv2_pass<3>(hs, w2t, wv, n, kg, acc);
        conv2_pass<4>(hs, w2t, wv, n, kg, acc);

        // ---- epilogue: out = sum_f filt_f * image[y+fy-1][x+fx-1].
        //      image read from GLOBAL (L1/L2-hot) instead of LDS; bounds
        //      predicate reproduces zero-pad; f>=9 terms are exact-zero. ----
        {
            const float* ib = image + (size_t)bb * (HH * WW);
            int fyv[4], fxv[4];
            #pragma unroll
            for (int r2 = 0; r2 < 4; ++r2) {
                unsigned int fp = (fppk >> (8 * r2)) & 0xFFu;
                fyv[r2] = (int)(fp >> 4);
                fxv[r2] = (int)(fp & 0xFu);
            }
            const int gxb = gx0 + n - 1;
            #pragma unroll
            for (int i = 0; i < 4; ++i) {
                int py  = wv * 4 + i;
                int gyb = gy0 + py - 1;
                float partial = 0.f;
                #pragma unroll
                for (int r2 = 0; r2 < 4; ++r2) {
                    int gy = gyb + fyv[r2];
                    int gx = gxb + fxv[r2];
                    bool inb = ((unsigned)gy < HH) & ((unsigned)gx < WW);
                    float img = inb ? ib[gy * WW + gx] : 0.f;
                    partial += acc[i][r2] * img;   // f>=9 term exact-zero
                }
                partial += __shfl_down(partial, 16, 64);
                partial += __shfl_down(partial, 32, 64);
                if (lane < 16)
                    out[((size_t)bb * HH + gy0 + py) * WW + gx0 + n] = partial;
            }
        }
        __syncthreads();   // C: pxc/hs free for next batch
    }
}

extern "C" void kernel_launch(void* const* d_in, const int* in_sizes, int n_in,
                              void* d_out, int out_size, void* d_ws, size_t ws_size,
                              hipStream_t stream) {
    const float* image = (const float*)d_in[0];
    const float* refer = (const float*)d_in[1];
    const float* w1    = (const float*)d_in[2];
    const float* b1    = (const float*)d_in[3];
    const float* w2    = (const float*)d_in[4];
    const float* b2    = (const float*)d_in[5];

    unsigned short* w1c = (unsigned short*)d_ws;                   // 4 KB
    unsigned short* w2t = (unsigned short*)((char*)d_ws + 4096);   // 25.6 KB
    // ws re-poisoned before every launch -> prep must (and does) run every call

    hipLaunchKernelGGL(dynfilt_prep, dim3(32), dim3(256), 0, stream, w1, w2, w1c, w2t);

    dim3 grid(WW / TILE, HH / TILE, 1);   // persistent over batch: 1024 blocks
    hipLaunchKernelGGL(dynfilt_main, grid, dim3(256), 0, stream,
                       image, refer, b1, b2, w1c, w2t, (float*)d_out);
}

// Round 19
// 137.955 us; speedup vs baseline: 1.1355x; 1.1355x over previous
//
#include <hip/hip_runtime.h>
#include <hip/hip_bf16.h>

// DynamicFilter fused, R33 = R31/R29 FINAL (verified 78.8us main, 139us e2e).
// R32's global-read epilogue reverted.
//
// R32 post-mortem (pre-committed revert condition hit): 78.8 -> 97.2us.
// Epilogue global-read machinery (64b addressing + 16 predicates) pushed
// the register peak past the 128 cap -> spills returned (WRITE 8.19 ->
// 17.0MB = ~8.8MB scratch). LDS relief was real but 10x smaller (conflicts
// 8.71e6 -> 7.91e6). Session lesson: in this kernel each marginal register
// outweighs any marginal LDS cycle.
// R31 is the verified optimum: register box closed (lower cap -> spills
// R17/18/19; higher -> residency cliff R30; more epilogue code -> spills
// R32); LDS stream at its structural floor (conv2 reads minimal, all
// phases ~2-way banks); occupancy closed both directions; HBM 6.6% idle.
// Ladder (main): 107 -> 95.6 (persistent batch + conv2 rolling) -> 93.2
// (k-perm gather) -> 88.2 (stride-39 epilogue) -> 86.5 (eopk arith) ->
// 78.8 (unified conv1 OOB-mask path, zero spill). -26% total.
//
// d_ws: w1c bf16 [32ch][64k] @0 (k-perm layout), w2t bf16 [25tap][16f]
// [32chpos] @4096 (f>=9 zero; chpos 2i->ch i, 2i+1->ch 16+i).
// k-perm: k = s*32+kg*8+2*j+ci ; s0: tap=(kg,j); s1,kg0: tap=(4,j);
// s1,kg1: tap=(j,4); s1,kg2,j0: tap=(4,4); else invalid (w1c=0).

typedef __attribute__((ext_vector_type(8))) short bf16x8;
typedef __attribute__((ext_vector_type(4))) float f32x4;

#define HH 512
#define WW 512
#define TILE 16
#define XS_H 24
#define XS_W 24
#define XS_N (XS_H * XS_W)     // 576
#define XSF 39                 // xs0f row stride in dwords (S+1=40 === 8 mod 32)
#define HS_R 20
#define HS_C 20
#define PXS 40                 // shorts per px in hs (80B stride)

__device__ __forceinline__ unsigned short f2bf(float x) {
    union { float f; unsigned int u; } v; v.f = x;
    unsigned int u = v.u;
    u += 0x7FFFu + ((u >> 16) & 1u);   // round-to-nearest-even
    return (unsigned short)(u >> 16);
}

__device__ __forceinline__ unsigned int pack_bf2(float a, float b) {
    __hip_bfloat162 h2 = __float22bfloat162_rn(make_float2(a, b));
    union { __hip_bfloat162 h; unsigned int u; } cv; cv.h = h2;
    return cv.u;
}

__device__ __forceinline__ bf16x8 dw4_to_frag(unsigned int d0, unsigned int d1,
                                              unsigned int d2, unsigned int d3) {
    union { unsigned int u[4]; bf16x8 f; } cv;
    cv.u[0] = d0; cv.u[1] = d1; cv.u[2] = d2; cv.u[3] = d3;
    return cv.f;
}

__global__ void dynfilt_prep(const float* __restrict__ w1,
                             const float* __restrict__ w2,
                             unsigned short* __restrict__ w1c,
                             unsigned short* __restrict__ w2t)
{
    int gid = blockIdx.x * 256 + threadIdx.x;   // 8192 threads
    // w1c[ch32][k64] with k-perm (see header); invalid slots -> 0
    for (int i = gid; i < 32 * 64; i += 8192) {
        int ch = i >> 6, k = i & 63;
        int s = (k >> 5) & 1, kg = (k >> 3) & 3, j = (k >> 1) & 3, ci = k & 1;
        int tap = 0; bool val = true;
        if (!s)            tap = kg * 5 + j;        // rows 0-3, cols 0-3
        else if (kg == 0)  tap = 20 + j;            // row 4, cols 0-3
        else if (kg == 1)  tap = j * 5 + 4;         // col 4, rows 0-3
        else if (kg == 2) { tap = 24; val = (j == 0); }   // corner (4,4)
        else               val = false;
        w1c[i] = val ? f2bf(w1[(ch * 2 + ci) * 25 + tap]) : (unsigned short)0;
    }
    // w2t[tap25][f16][chpos32]: chpos 2i -> ch i, 2i+1 -> ch 16+i; f>=9 zero
    for (int i = gid; i < 25 * 16 * 32; i += 8192) {
        int p = i & 31;
        int f = (i >> 5) & 15;
        int tap = i >> 9;   // 0..24
        int ch = (p & 1) * 16 + (p >> 1);
        w2t[i] = (f < 9) ? f2bf(w2[(f * 32 + ch) * 25 + tap]) : (unsigned short)0;
    }
}

// conv2 pass over single tap-col TC0: rolling 4-row B-frag buffer.
// B-frag(row = wv*4 + i + tr, col = n + TC0) shared across (i,tr) with equal
// i+tr; rows rotate through R[.&3]. All indices compile-time after unroll.
template<int TC0>
__device__ __forceinline__ void conv2_pass(const unsigned short* hsp,
                                           const unsigned short* __restrict__ w2t,
                                           int wv, int n, int kg, f32x4* acc) {
    bf16x8 R[4];
    #pragma unroll
    for (int q = 0; q < 4; ++q)
        R[q] = *(const bf16x8*)(hsp + ((wv * 4 + q) * HS_C + n + TC0) * PXS + kg * 8);
    #pragma unroll
    for (int tr = 0; tr < 5; ++tr) {
        bf16x8 afr = *(const bf16x8*)(w2t + ((tr * 5 + TC0) * 16 + n) * 32 + kg * 8);
        #pragma unroll
        for (int i = 0; i < 4; ++i)
            acc[i] = __builtin_amdgcn_mfma_f32_16x16x32_bf16(afr, R[(tr + i) & 3], acc[i], 0, 0, 0);
        if (tr < 4)
            R[tr & 3] = *(const bf16x8*)(hsp + ((wv * 4 + tr + 4) * HS_C + n + TC0) * PXS + kg * 8);
    }
}

__global__
__attribute__((amdgpu_flat_work_group_size(256, 256), amdgpu_waves_per_eu(2)))
void dynfilt_main(const float* __restrict__ image,
                  const float* __restrict__ refer,
                  const float* __restrict__ b1,
                  const float* __restrict__ b2,
                  const unsigned short* __restrict__ w1c,
                  const unsigned short* __restrict__ w2t,
                  float* __restrict__ out)
{
    __shared__ float xs0f[XS_H * XSF];          // image fp32, stride-39 rows
    __shared__ unsigned int pxc[XS_N];          // packed (bf16 img | bf16 ref)
    __shared__ __align__(16) unsigned short hs[HS_R * HS_C * PXS];

    const int t   = threadIdx.x;
    const int gx0 = blockIdx.x * TILE;
    const int gy0 = blockIdx.y * TILE;

    // ---- batch-invariant staging offsets (sentinel -1 = skip) ----
    int soff[3];
    #pragma unroll
    for (int k = 0; k < 3; ++k) {
        int idx = t + k * 256;
        int r = idx / XS_W, c = idx - (idx / XS_W) * XS_W;
        int gy = gy0 - 4 + r, gx = gx0 - 4 + c;
        bool inb = (idx < XS_N) & ((unsigned)gy < HH) & ((unsigned)gx < WW);
        soff[k] = inb ? (gy * WW + gx) : -1;
    }

    const int lane = t & 63;
    const int wv   = t >> 6;
    const int n    = lane & 15;
    const int kg   = lane >> 4;

    // ---- conv1 B-frags: loaded ONCE, carried (w1c L1-hot) ----
    bf16x8 bfr[2][2];
    #pragma unroll
    for (int nt = 0; nt < 2; ++nt)
        #pragma unroll
        for (int s = 0; s < 2; ++s)
            bfr[nt][s] = *(const bf16x8*)(w1c + (nt * 16 + n) * 64 + s * 32 + kg * 8);

    // ---- a1 gather offsets (k-perm layout), packed 4x8bit; invalid -> 0
    //      (broadcast read, zero weight in w1c makes the product exact-0) ----
    unsigned int a1opk = 0;
    #pragma unroll
    for (int j = 0; j < 4; ++j) {
        int o = (kg == 0) ? (4 * XS_W + j)                  // row 4, col j
              : (kg == 1) ? (j * XS_W + 4)                  // row j, col 4
              : (kg == 2 && j == 0) ? (4 * XS_W + 4) : 0;   // corner / dummy
        a1opk |= (unsigned)o << (8 * j);
    }

    // ---- batch-invariant conv1 OOB mask: bit (m*4+r) = h px in-bounds ----
    // px = m*64 + wv*16 + kg*4 + r; divisions happen ONCE per block here,
    // never in the batch loop. Interior blocks get all-ones.
    unsigned int obmask = 0;
    #pragma unroll
    for (int m = 0; m < 7; ++m) {
        #pragma unroll
        for (int r = 0; r < 4; ++r) {
            int px = m * 64 + wv * 16 + kg * 4 + r;
            if (px < 400) {
                int prr = px / HS_C, pcc = px - prr * HS_C;
                int gy = gy0 - 2 + prr, gx = gx0 - 2 + pcc;
                if (((unsigned)gy < HH) & ((unsigned)gx < WW))
                    obmask |= 1u << (m * 4 + r);
            }
        }
    }

    // px = mt*16 + n raster start (pr0,pc0) over 20-wide h grid
    int px0 = wv * 16 + n;
    const int pr0 = px0 / 20, pc0 = px0 - (px0 / 20) * 20;

    const float bb0 = b1[n], bb1 = b1[16 + n];

    // ---- conv2 / epilogue constants (once); eo packed 4x8bit.
    //      Valid f: eo = (fy+3)*39 + fx+3. Invalid f>=9: bank-filler slots
    //      computed arithmetically: idx=f-9 -> e = 137+idx+4*((idx+1)/3)
    //      = {137,138,143,144,145,150,151}; all reads 2 lanes/bank. ----
    float b2r[4];
    unsigned int eopk = 0;
    #pragma unroll
    for (int r2 = 0; r2 < 4; ++r2) {
        int f = kg * 4 + r2;
        b2r[r2] = (f < 9) ? b2[f] : 0.f;
        unsigned int e;
        if (f < 9) {
            int fy = f / 3, fx = f - fy * 3;
            e = (unsigned)((fy + 3) * XSF + fx + 3);   // 120..200
        } else {
            int idx = f - 9;                           // 0..6
            e = 137u + (unsigned)idx + 4u * (unsigned)((idx + 1) / 3);
        }
        eopk |= e << (8 * r2);
    }

    // ---- prefetch batch 0 halo into regs ----
    float pvI[3], pvR[3];
    #pragma unroll
    for (int k = 0; k < 3; ++k) {
        pvI[k] = 0.f; pvR[k] = 0.f;
        if (soff[k] >= 0) {
            pvI[k] = image[soff[k]];
            pvR[k] = refer[soff[k]];
        }
    }

    #pragma unroll 1
    for (int bb = 0; bb < 8; ++bb) {
        // ---- stage write from prefetch regs ----
        #pragma unroll
        for (int k = 0; k < 3; ++k) {
            int idx = t + k * 256;
            if (idx < XS_N) {
                int r = idx / XS_W, c = idx - (idx / XS_W) * XS_W;
                xs0f[r * XSF + c] = pvI[k];
                pxc[idx] = pack_bf2(pvI[k], pvR[k]);
            }
        }
        __syncthreads();   // A: xs0f/pxc ready

        // ---- issue next batch's prefetch (hides under conv1+conv2) ----
        if (bb < 7) {
            const float* ibn = image + (size_t)(bb + 1) * (HH * WW);
            const float* rbn = refer + (size_t)(bb + 1) * (HH * WW);
            #pragma unroll
            for (int k = 0; k < 3; ++k) {
                pvI[k] = 0.f; pvR[k] = 0.f;
                if (soff[k] >= 0) {
                    pvI[k] = ibn[soff[k]];
                    pvR[k] = rbn[soff[k]];
                }
            }
        }

        // ---- unpack a1 offsets (conv1-local regs) ----
        int a1o[4];
        #pragma unroll
        for (int j = 0; j < 4; ++j)
            a1o[j] = (int)((a1opk >> (8 * j)) & 0xFFu);

        // ---- conv1 GEMM + fused leaky+pack write to hs (UNIFIED path) ----
        int pr = pr0, pc = pc0;
        unsigned short* hp0 = hs + (wv * 16 + kg * 4) * PXS + 2 * n;
        #pragma unroll
        for (int m = 0; m < 7; ++m) {
            int mt = m * 4 + wv;
            if (mt < 25) {   // wave-uniform guard
                const unsigned int* base = pxc + (pr * XS_W + pc);
                const unsigned int* a0p  = base + kg * XS_W;   // row kg
                unsigned int a0d[4], a1d[4];
                #pragma unroll
                for (int j = 0; j < 4; ++j) a0d[j] = a0p[j];
                #pragma unroll
                for (int j = 0; j < 4; ++j) a1d[j] = base[a1o[j]];
                bf16x8 a0 = dw4_to_frag(a0d[0], a0d[1], a0d[2], a0d[3]);
                bf16x8 a1 = dw4_to_frag(a1d[0], a1d[1], a1d[2], a1d[3]);
                f32x4 d0 = (f32x4){bb0, bb0, bb0, bb0};
                f32x4 d1 = (f32x4){bb1, bb1, bb1, bb1};
                d0 = __builtin_amdgcn_mfma_f32_16x16x32_bf16(a0, bfr[0][0], d0, 0, 0, 0);
                d0 = __builtin_amdgcn_mfma_f32_16x16x32_bf16(a1, bfr[0][1], d0, 0, 0, 0);
                d1 = __builtin_amdgcn_mfma_f32_16x16x32_bf16(a0, bfr[1][0], d1, 0, 0, 0);
                d1 = __builtin_amdgcn_mfma_f32_16x16x32_bf16(a1, bfr[1][1], d1, 0, 0, 0);
                #pragma unroll
                for (int r = 0; r < 4; ++r) {
                    float h0 = fmaxf(d0[r], 0.1f * d0[r]);
                    float h1 = fmaxf(d1[r], 0.1f * d1[r]);
                    if (!((obmask >> (m * 4 + r)) & 1u)) { h0 = 0.f; h1 = 0.f; }
                    *(unsigned int*)(hp0 + (m * 64 + r) * PXS) = pack_bf2(h0, h1);
                }
            }
            pc += 4; pr += 3;
            int w = (pc >= 20) ? 1 : 0;
            pc -= 20 * w; pr += w;
        }
        __syncthreads();   // B: hs ready

        // ---- conv2: rolling-row MFMA GEMM (5 single-col passes), b2-init ----
        f32x4 acc[4];
        #pragma unroll
        for (int i = 0; i < 4; ++i)
            acc[i] = (f32x4){b2r[0], b2r[1], b2r[2], b2r[3]};

        conv2_pass<0>(hs, w2t, wv, n, kg, acc);
        conv2_pass<1>(hs, w2t, wv, n, kg, acc);
        conv2_pass<2>(hs, w2t, wv, n, kg, acc);
        conv2_pass<3>(hs, w2t, wv, n, kg, acc);
        conv2_pass<4>(hs, w2t, wv, n, kg, acc);

        // ---- epilogue: out = sum_f filt_f * image[y+fy-1][x+fx-1] ----
        int eo[4];
        #pragma unroll
        for (int r2 = 0; r2 < 4; ++r2)
            eo[r2] = (int)((eopk >> (8 * r2)) & 0xFFu);
        #pragma unroll
        for (int i = 0; i < 4; ++i) {
            int py = wv * 4 + i;
            const float* xb = xs0f + py * XSF + n;
            float partial = 0.f;
            #pragma unroll
            for (int r2 = 0; r2 < 4; ++r2)
                partial += acc[i][r2] * xb[eo[r2]];   // f>=9 term exact-zero
            partial += __shfl_down(partial, 16, 64);
            partial += __shfl_down(partial, 32, 64);
            if (lane < 16)
                out[((size_t)bb * HH + gy0 + py) * WW + gx0 + n] = partial;
        }
        __syncthreads();   // C: xs0f/pxc/hs free for next batch
    }
}

extern "C" void kernel_launch(void* const* d_in, const int* in_sizes, int n_in,
                              void* d_out, int out_size, void* d_ws, size_t ws_size,
                              hipStream_t stream) {
    const float* image = (const float*)d_in[0];
    const float* refer = (const float*)d_in[1];
    const float* w1    = (const float*)d_in[2];
    const float* b1    = (const float*)d_in[3];
    const float* w2    = (const float*)d_in[4];
    const float* b2    = (const float*)d_in[5];

    unsigned short* w1c = (unsigned short*)d_ws;                   // 4 KB
    unsigned short* w2t = (unsigned short*)((char*)d_ws + 4096);   // 25.6 KB
    // ws re-poisoned before every launch -> prep must (and does) run every call

    hipLaunchKernelGGL(dynfilt_prep, dim3(32), dim3(256), 0, stream, w1, w2, w1c, w2t);

    dim3 grid(WW / TILE, HH / TILE, 1);   // persistent over batch: 1024 blocks
    hipLaunchKernelGGL(dynfilt_main, grid, dim3(256), 0, stream,
                       image, refer, b1, b2, w1c, w2t, (float*)d_out);
}